// Round 9
// baseline (397.644 us; speedup 1.0000x reference)
//
#include <hip/hip_runtime.h>

#define N_NODES 100000
#define N_EDGES 1600000
#define IN_DIM 128
#define HID 64
#define NB 782               // ceil(100000 / 128) buckets of 128 nodes
#define NGEMM 6250           // N_NODES / 16 row-tiles (exact)
#define NGROUP 25000         // N_NODES / 4 agg groups
#define PART_BLOCKS 391      // ceil(N_EDGES / 4096)

typedef __attribute__((ext_vector_type(8))) _Float16 h8v;
typedef __attribute__((ext_vector_type(4))) float f4v;

struct Args {
  const float* x; const int* ei;
  const float* Wp; const float* bp;
  const float* W1; const float* b1;
  const float* W2; const float* b2;
  const float* W3; const float* b3;
  float* out;
  _Float16* bufA16; _Float16* hw16;   // hw16 has N_NODES+1 rows (row N = zeros)
  int* pairs; int* csr; int* offs; float* dinv;
  int* bsz; int* bboff; int* bcur;
  _Float16* WpH; _Float16* WpL; _Float16* W1H; _Float16* W1L;
  _Float16* W2H; _Float16* W2L; _Float16* W3H; _Float16* W3L;
};

// ---------------- weight prep + zero sentinel row ----------------
__device__ __forceinline__ void d_split(const float* __restrict__ W,
                                        _Float16* __restrict__ hi,
                                        _Float16* __restrict__ lo, int K, int i) {
  int k = i >> 6, n = i & 63;
  float v = W[i];
  _Float16 h = (_Float16)v;
  float r = v - (float)h;
  hi[n * K + k] = h;
  lo[n * K + k] = (_Float16)r;
}

__global__ __launch_bounds__(256) void f_prep(Args a) {
  int blk = blockIdx.x, t = threadIdx.x;
  if (blk < 32) d_split(a.Wp, a.WpH, a.WpL, IN_DIM, blk * 256 + t);
  else if (blk < 48) d_split(a.W1, a.W1H, a.W1L, HID, (blk - 32) * 256 + t);
  else if (blk < 64) d_split(a.W2, a.W2H, a.W2L, HID, (blk - 48) * 256 + t);
  else if (blk < 80) d_split(a.W3, a.W3H, a.W3L, HID, (blk - 64) * 256 + t);
  else if (t < HID) a.hw16[(size_t)N_NODES * HID + t] = (_Float16)0.f;  // sentinel row
}

// ---------------- bucket histogram ----------------
__global__ __launch_bounds__(256) void f_bhist(Args a) {
  __shared__ int cnt[NB];
  int t = threadIdx.x;
  for (int i = t; i < NB; i += 256) cnt[i] = 0;
  __syncthreads();
  int e0 = blockIdx.x * 4096, e1 = min(e0 + 4096, N_EDGES);
  for (int e = e0 + t; e < e1; e += 256)
    atomicAdd(&cnt[a.ei[N_EDGES + e] >> 7], 1);
  __syncthreads();
  for (int i = t; i < NB; i += 256)
    if (cnt[i]) atomicAdd(&a.bsz[i], cnt[i]);
}

// ---------------- bucket exclusive scan (1 block, 256 thr x 4 slots) ----------
__global__ __launch_bounds__(256) void f_bscan(Args a) {
  __shared__ int sm[256];
  int t = threadIdx.x;
  int c[4];
  int idx0 = t * 4;
#pragma unroll
  for (int j = 0; j < 4; ++j) c[j] = (idx0 + j < NB) ? a.bsz[idx0 + j] : 0;
  int tsum = c[0] + c[1] + c[2] + c[3];
  int val = tsum;
  sm[t] = val;
  __syncthreads();
  for (int off = 1; off < 256; off <<= 1) {
    int u = (t >= off) ? sm[t - off] : 0;
    __syncthreads();
    val += u;
    sm[t] = val;
    __syncthreads();
  }
  int excl = val - tsum;
#pragma unroll
  for (int j = 0; j < 4; ++j) {
    int idx = idx0 + j;
    if (idx < NB) { a.bboff[idx] = excl; a.bcur[idx] = excl; }
    excl += c[j];
  }
  if (t == 255) a.bboff[NB] = val;  // == N_EDGES
}

// ---------------- partition edges into buckets; pack (dlocal<<17 | src) --------
__global__ __launch_bounds__(256) void f_partition(Args a) {
  __shared__ int cnt[NB];
  __shared__ int base[NB];
  int t = threadIdx.x;
  for (int i = t; i < NB; i += 256) cnt[i] = 0;
  __syncthreads();
  int e0 = blockIdx.x * 4096, e1 = min(e0 + 4096, N_EDGES);
  for (int e = e0 + t; e < e1; e += 256)
    atomicAdd(&cnt[a.ei[N_EDGES + e] >> 7], 1);
  __syncthreads();
  for (int i = t; i < NB; i += 256) {
    int c = cnt[i];
    base[i] = c ? atomicAdd(&a.bcur[i], c) : 0;
    cnt[i] = 0;
  }
  __syncthreads();
  for (int e = e0 + t; e < e1; e += 256) {
    int s = a.ei[e];
    int d = a.ei[N_EDGES + e];
    int b = d >> 7;
    int r = atomicAdd(&cnt[b], 1);
    a.pairs[base[b] + r] = ((d & 127) << 17) | s;
  }
}

// ---------------- per-bucket degrees + offs + dinv + CSR scatter ---------------
__global__ __launch_bounds__(256) void f_csrdeg(Args a) {
  __shared__ int ldeg[128];
  __shared__ int sc[128];
  __shared__ int lcur[128];
  int t = threadIdx.x;
  int b = blockIdx.x;
  int node0 = b << 7;
  int nloc = min(128, N_NODES - node0);
  int beg = a.bboff[b], end = a.bboff[b + 1];
  if (t < 128) ldeg[t] = 0;
  __syncthreads();
  for (int i = beg + t; i < end; i += 256)
    atomicAdd(&ldeg[(a.pairs[i] >> 17) & 127], 1);
  __syncthreads();
  int dv = (t < 128) ? ldeg[t] : 0;
  if (t < 128) sc[t] = dv;
  __syncthreads();
  for (int off = 1; off < 128; off <<= 1) {
    int u = (t >= off && t < 128) ? sc[t - off] : 0;
    __syncthreads();
    if (t < 128) sc[t] += u;
    __syncthreads();
  }
  if (t < nloc) {
    int o = beg + sc[t] - dv;
    a.offs[node0 + t] = o;
    lcur[t] = o;
    a.dinv[node0 + t] = rsqrtf((float)dv + 1.0f);
  }
  if (b == NB - 1 && t == 0) a.offs[N_NODES] = N_EDGES;
  __syncthreads();
  for (int i = beg + t; i < end; i += 256) {
    int p = a.pairs[i];
    int pos = atomicAdd(&lcur[(p >> 17) & 127], 1);
    a.csr[pos] = p & 131071;
  }
}

// ---- pre GEMM (col-split): block = 16 rows, wave w = cols [16w,16w+16) ----
// fp32 A split hi/lo (3 MFMAs per k-step), +bias, out fp16 (unscaled)
__global__ __launch_bounds__(256) void f_gemm_pre(Args a) {
  const int K = IN_DIM;
  int w = threadIdx.x >> 6;
  int lane = threadIdx.x & 63;
  int fi = lane & 15;
  int quad = lane >> 4;
  int r0 = blockIdx.x * 16;
  const float* xp = a.x + (size_t)(r0 + fi) * K + quad * 8;

  f4v acc = {0.f, 0.f, 0.f, 0.f};
#pragma unroll
  for (int k0 = 0; k0 < K; k0 += 32) {
    f4v xa = *(const f4v*)(xp + k0);
    f4v xb = *(const f4v*)(xp + k0 + 4);
    h8v ah, al;
#pragma unroll
    for (int j = 0; j < 4; ++j) {
      _Float16 h = (_Float16)xa[j];
      ah[j] = h;
      al[j] = (_Float16)(xa[j] - (float)h);
    }
#pragma unroll
    for (int j = 0; j < 4; ++j) {
      _Float16 h = (_Float16)xb[j];
      ah[4 + j] = h;
      al[4 + j] = (_Float16)(xb[j] - (float)h);
    }
    const _Float16* whp = a.WpH + (size_t)(w * 16 + fi) * K + k0 + quad * 8;
    const _Float16* wlp = a.WpL + (size_t)(w * 16 + fi) * K + k0 + quad * 8;
    h8v bh = *(const h8v*)whp;
    h8v bl = *(const h8v*)wlp;
    acc = __builtin_amdgcn_mfma_f32_16x16x32_f16(ah, bh, acc, 0, 0, 0);
    acc = __builtin_amdgcn_mfma_f32_16x16x32_f16(al, bh, acc, 0, 0, 0);
    acc = __builtin_amdgcn_mfma_f32_16x16x32_f16(ah, bl, acc, 0, 0, 0);
  }
  float bv = a.bp[w * 16 + fi];
#pragma unroll
  for (int j = 0; j < 4; ++j) {
    int orow = r0 + quad * 4 + j;
    a.bufA16[(size_t)orow * HID + w * 16 + fi] = (_Float16)(acc[j] + bv);
  }
}

// ---- hidden GEMM (col-split): fp16 A exact, 2 MFMAs per k-step,
//      epilogue scales row by dinv[row] -> hw'[r] = (h@W)[r] * dinv[r] ----
__global__ __launch_bounds__(256) void f_gemm64(Args a, const _Float16* __restrict__ Wh,
                                                const _Float16* __restrict__ Wl) {
  const int K = HID;
  int w = threadIdx.x >> 6;
  int lane = threadIdx.x & 63;
  int fi = lane & 15;
  int quad = lane >> 4;
  int r0 = blockIdx.x * 16;
  const _Float16* xp = a.bufA16 + (size_t)(r0 + fi) * K + quad * 8;

  f4v acc = {0.f, 0.f, 0.f, 0.f};
#pragma unroll
  for (int k0 = 0; k0 < K; k0 += 32) {
    h8v av = *(const h8v*)(xp + k0);
    const _Float16* whp = Wh + (size_t)(w * 16 + fi) * K + k0 + quad * 8;
    const _Float16* wlp = Wl + (size_t)(w * 16 + fi) * K + k0 + quad * 8;
    h8v bh = *(const h8v*)whp;
    h8v bl = *(const h8v*)wlp;
    acc = __builtin_amdgcn_mfma_f32_16x16x32_f16(av, bh, acc, 0, 0, 0);
    acc = __builtin_amdgcn_mfma_f32_16x16x32_f16(av, bl, acc, 0, 0, 0);
  }
#pragma unroll
  for (int j = 0; j < 4; ++j) {
    int orow = r0 + quad * 4 + j;
    a.hw16[(size_t)orow * HID + w * 16 + fi] = (_Float16)(acc[j] * a.dinv[orow]);
  }
}

// ---- aggregation: wave/node, oct-parallel, 4-deep; unweighted sum of
//      pre-scaled rows; sentinel zero-row for invalid slots; epilogue *di+bias ----
template <int MODE>
__device__ __forceinline__ void d_agg(int grp, const _Float16* __restrict__ hw,
                                      const int* __restrict__ offs,
                                      const int* __restrict__ csr,
                                      const float* __restrict__ dinv,
                                      const float* __restrict__ bias,
                                      _Float16* __restrict__ out16,
                                      float* __restrict__ out32) {
  int node = grp * 4 + (threadIdx.x >> 6);
  int lane = threadIdx.x & 63;
  int oct = lane >> 3;
  int fi = lane & 7;
  float di = dinv[node];
  int beg = offs[node];
  int end = offs[node + 1];

  float acc[8];
#pragma unroll
  for (int c = 0; c < 8; ++c) acc[c] = 0.f;

  if (oct == 0) {  // self term: hw'[node] (weight folded: di applied in epilogue)
    h8v hv = *(const h8v*)(hw + (size_t)node * HID + fi * 8);
#pragma unroll
    for (int c = 0; c < 8; ++c) acc[c] += (float)hv[c];
  }
  for (int e0 = beg + oct; e0 < end; e0 += 32) {
    int ss[4];
#pragma unroll
    for (int j = 0; j < 4; ++j) {
      int e = e0 + 8 * j;
      int s = csr[min(e, end - 1)];
      ss[j] = (e < end) ? s : N_NODES;  // sentinel zero row
    }
    h8v hv[4];
#pragma unroll
    for (int j = 0; j < 4; ++j)
      hv[j] = *(const h8v*)(hw + (size_t)ss[j] * HID + fi * 8);
    h8v hs = (hv[0] + hv[1]) + (hv[2] + hv[3]);  // packed fp16 pairwise tree
#pragma unroll
    for (int c = 0; c < 8; ++c) acc[c] += (float)hs[c];
  }
#pragma unroll
  for (int c = 0; c < 8; ++c) {
    float v = acc[c];
    v += __shfl_xor(v, 8);
    v += __shfl_xor(v, 16);
    v += __shfl_xor(v, 32);
    acc[c] = v;
  }
  if (oct == 0) {
#pragma unroll
    for (int c = 0; c < 8; ++c) acc[c] = acc[c] * di + bias[fi * 8 + c];
    if (MODE == 0) {
      h8v o;
#pragma unroll
      for (int c = 0; c < 8; ++c) o[c] = (_Float16)fmaxf(acc[c], 0.f);
      *(h8v*)(out16 + (size_t)node * HID + fi * 8) = o;
    } else {
      float ss = 0.f;
#pragma unroll
      for (int c = 0; c < 8; ++c) ss += acc[c] * acc[c];
      ss += __shfl_xor(ss, 1);
      ss += __shfl_xor(ss, 2);
      ss += __shfl_xor(ss, 4);
      float sc = 1.0f / fmaxf(sqrtf(ss), 1e-12f);
      f4v o0 = {acc[0] * sc, acc[1] * sc, acc[2] * sc, acc[3] * sc};
      f4v o1 = {acc[4] * sc, acc[5] * sc, acc[6] * sc, acc[7] * sc};
      *(f4v*)(out32 + (size_t)node * HID + fi * 8) = o0;
      *(f4v*)(out32 + (size_t)node * HID + fi * 8 + 4) = o1;
    }
  }
}

__global__ __launch_bounds__(256) void f_agg_relu(Args a, const float* bias) {
  d_agg<0>(blockIdx.x, a.hw16, a.offs, a.csr, a.dinv, bias, a.bufA16, nullptr);
}

__global__ __launch_bounds__(256) void f_agg_norm(Args a) {
  d_agg<1>(blockIdx.x, a.hw16, a.offs, a.csr, a.dinv, a.b3, nullptr, a.out);
}

extern "C" void kernel_launch(void* const* d_in, const int* in_sizes, int n_in,
                              void* d_out, int out_size, void* d_ws, size_t ws_size,
                              hipStream_t stream) {
  char* ws = (char*)d_ws;
  Args a;
  a.x  = (const float*)d_in[0];
  a.ei = (const int*)d_in[1];
  a.Wp = (const float*)d_in[2];  a.bp = (const float*)d_in[3];
  a.W1 = (const float*)d_in[4];  a.b1 = (const float*)d_in[5];
  a.W2 = (const float*)d_in[6];  a.b2 = (const float*)d_in[7];
  a.W3 = (const float*)d_in[8];  a.b3 = (const float*)d_in[9];
  a.out  = (float*)d_out;
  a.bufA16 = (_Float16*)(ws + 0);             // 12.8 MB fp16 activations
  a.hw16   = (_Float16*)(ws + 12800000);      // 12.8 MB + sentinel row
  a.pairs  = (int*)(ws + 25600256);           // 6.4 MB packed (dlocal<<17|src)
  a.csr    = (int*)(ws + 32000256);           // 6.4 MB
  a.offs   = (int*)(ws + 38400256);           // (N+1) ints
  a.dinv   = (float*)(ws + 38800264);         // 400 KB
  a.bsz    = (int*)(ws + 39200264);           // NB ints
  a.bboff  = (int*)(ws + 39203400);           // NB+1 ints
  a.bcur   = (int*)(ws + 39206536);           // NB ints
  a.WpH = (_Float16*)(ws + 39209672);         // 16 KB
  a.WpL = (_Float16*)(ws + 39226056);
  a.W1H = (_Float16*)(ws + 39242440);         // 8 KB each
  a.W1L = (_Float16*)(ws + 39250632);
  a.W2H = (_Float16*)(ws + 39258824);
  a.W2L = (_Float16*)(ws + 39267016);
  a.W3H = (_Float16*)(ws + 39275208);
  a.W3L = (_Float16*)(ws + 39283400);

  (void)hipMemsetAsync(a.bsz, 0, NB * sizeof(int), stream);
  f_prep<<<81, 256, 0, stream>>>(a);
  f_bhist<<<PART_BLOCKS, 256, 0, stream>>>(a);
  f_bscan<<<1, 256, 0, stream>>>(a);
  f_partition<<<PART_BLOCKS, 256, 0, stream>>>(a);
  f_csrdeg<<<NB, 256, 0, stream>>>(a);
  f_gemm_pre<<<NGEMM, 256, 0, stream>>>(a);
  f_gemm64<<<NGEMM, 256, 0, stream>>>(a, a.W1H, a.W1L);
  f_agg_relu<<<NGROUP, 256, 0, stream>>>(a, a.b1);
  f_gemm64<<<NGEMM, 256, 0, stream>>>(a, a.W2H, a.W2L);
  f_agg_relu<<<NGROUP, 256, 0, stream>>>(a, a.b2);
  f_gemm64<<<NGEMM, 256, 0, stream>>>(a, a.W3H, a.W3L);
  f_agg_norm<<<NGROUP, 256, 0, stream>>>(a);
}